// Round 3
// baseline (116.831 us; speedup 1.0000x reference)
//
#include <hip/hip_runtime.h>

// Problem constants
constexpr int B_ = 2;
constexpr int S_ = 2048;
constexpr int E_ = 1024;

// Column-sum decomposition
constexpr int SCHUNK = 128;                    // number of s-chunks
constexpr int ROWS_PER_CHUNK = S_ / SCHUNK;    // 16 rows each

// ------------------------------------------------------------------
// Kernel A: partial column sums of values[b, s, e] over s within a chunk.
// grid = B_*SCHUNK = 256 blocks, 256 threads. Thread t owns float4 column t.
// Fully coalesced: a wave reads 1 KB contiguous per row.
// ------------------------------------------------------------------
__global__ void partial_colsum_kernel(const float4* __restrict__ vals,
                                      float4* __restrict__ partial) {
    const int blk = blockIdx.x;
    const int b = blk / SCHUNK;
    const int chunk = blk % SCHUNK;
    const int t = threadIdx.x;  // 0..255 -> float4 column index (E/4 = 256)

    const float4* src = vals + (size_t)(b * S_ + chunk * ROWS_PER_CHUNK) * (E_ / 4) + t;
    float4 acc = make_float4(0.f, 0.f, 0.f, 0.f);
#pragma unroll
    for (int r = 0; r < ROWS_PER_CHUNK; ++r) {
        float4 v = src[(size_t)r * (E_ / 4)];
        acc.x += v.x; acc.y += v.y; acc.z += v.z; acc.w += v.w;
    }
    partial[(size_t)(b * SCHUNK + chunk) * (E_ / 4) + t] = acc;
}

// ------------------------------------------------------------------
// Kernel A2: reduce partials -> colsum[b*E + e].
// grid = B_*E_/256 = 8 blocks, 256 threads.
// ------------------------------------------------------------------
__global__ void reduce_colsum_kernel(const float* __restrict__ partial,
                                     float* __restrict__ colsum) {
    const int idx = blockIdx.x * 256 + threadIdx.x;  // 0..B*E-1
    const int b = idx / E_;
    const int e = idx % E_;
    float acc = 0.f;
#pragma unroll 8
    for (int c = 0; c < SCHUNK; ++c) {
        acc += partial[(size_t)(b * SCHUNK + c) * E_ + e];
    }
    colsum[idx] = acc;
}

// ------------------------------------------------------------------
// Kernel B: r[b,j] = dot(colsum[b,:], Wv[j,:]) + S*bv[j]
// One wave per output j; 4 waves (4 outputs) per block; 512 blocks.
// ------------------------------------------------------------------
__global__ void gemv_r_kernel(const float* __restrict__ colsum,
                              const float* __restrict__ Wv,
                              const float* __restrict__ bv,
                              float* __restrict__ r) {
    const int wave = threadIdx.x >> 6;
    const int lane = threadIdx.x & 63;
    const int out_idx = blockIdx.x * 4 + wave;  // 0..B*E-1
    const int b = out_idx >> 10;                // / E_
    const int j = out_idx & (E_ - 1);

    const float4* wrow = (const float4*)(Wv + (size_t)j * E_);
    const float4* cs = (const float4*)(colsum + (size_t)b * E_);

    float acc = 0.f;
#pragma unroll
    for (int i = 0; i < 4; ++i) {
        float4 w = wrow[lane + 64 * i];
        float4 c = cs[lane + 64 * i];
        acc += w.x * c.x + w.y * c.y + w.z * c.z + w.w * c.w;
    }
    // wave-wide reduction (64 lanes)
#pragma unroll
    for (int off = 32; off > 0; off >>= 1) acc += __shfl_down(acc, off, 64);

    if (lane == 0) r[out_idx] = acc + (float)S_ * bv[j];
}

// ------------------------------------------------------------------
// Kernel C: broadcast r over the q axis.
// out[b,q,j] = r[b,j]; float4 granularity. 1M float4 stores.
// grid = 4096 blocks, 256 threads, 1 float4 each.
// ------------------------------------------------------------------
__global__ void broadcast_out_kernel(const float4* __restrict__ r,
                                     float4* __restrict__ out) {
    const size_t idx = (size_t)blockIdx.x * 256 + threadIdx.x;  // float4 index
    const int j4 = (int)(idx & 255);         // E/4 = 256 float4 cols
    const int b = (int)(idx >> 19);          // / (S_ * 256)
    out[idx] = r[(b << 8) + j4];
}

// ------------------------------------------------------------------
// kernel_launch
// Inputs (setup_inputs order):
//   0: values [B,S,E] f32   (used)
//   1: keys                 (unused - einsum degeneracy)
//   2: queries              (unused)
//   3: Wq  4: bq  5: Wk  6: bk   (unused)
//   7: Wv [E,E] f32 (used)  8: bv [E] f32 (used)
// Output: [B,S,H,D] f32 = [2,2048,16,64] flat = [B,S,E].
// ------------------------------------------------------------------
extern "C" void kernel_launch(void* const* d_in, const int* in_sizes, int n_in,
                              void* d_out, int out_size, void* d_ws, size_t ws_size,
                              hipStream_t stream) {
    const float* values = (const float*)d_in[0];
    const float* Wv = (const float*)d_in[7];
    const float* bv = (const float*)d_in[8];
    float* out = (float*)d_out;

    // ws layout (floats): partial[B*SCHUNK*E], colsum[B*E], r[B*E]
    float* partial = (float*)d_ws;
    float* colsum = partial + (size_t)B_ * SCHUNK * E_;
    float* r = colsum + (size_t)B_ * E_;

    partial_colsum_kernel<<<B_ * SCHUNK, 256, 0, stream>>>((const float4*)values,
                                                           (float4*)partial);
    reduce_colsum_kernel<<<(B_ * E_) / 256, 256, 0, stream>>>(partial, colsum);
    gemv_r_kernel<<<(B_ * E_) / 4, 256, 0, stream>>>(colsum, Wv, bv, r);
    broadcast_out_kernel<<<(size_t)(B_ * S_ * E_) / 4 / 256, 256, 0, stream>>>(
        (const float4*)r, (float4*)out);
}

// Round 4
// 113.012 us; speedup vs baseline: 1.0338x; 1.0338x over previous
//
#include <hip/hip_runtime.h>

// Problem constants
constexpr int B_ = 2;
constexpr int S_ = 2048;
constexpr int E_ = 1024;

// Column-sum decomposition
constexpr int SCHUNK = 256;                    // number of s-chunks per batch
constexpr int ROWS_PER_CHUNK = S_ / SCHUNK;    // 8 rows each

// ------------------------------------------------------------------
// Kernel A: partial column sums of values[b, s, e] over s within a chunk.
// grid = B_*SCHUNK = 512 blocks (2 blocks/CU), 256 threads.
// Thread t owns float4 column t; 8 independent loads of ILP.
// Fully coalesced: a wave reads 1 KB contiguous per row.
// ------------------------------------------------------------------
__global__ void partial_colsum_kernel(const float4* __restrict__ vals,
                                      float4* __restrict__ partial) {
    const int blk = blockIdx.x;
    const int b = blk / SCHUNK;
    const int chunk = blk % SCHUNK;
    const int t = threadIdx.x;  // 0..255 -> float4 column index (E/4 = 256)

    const float4* src = vals + (size_t)(b * S_ + chunk * ROWS_PER_CHUNK) * (E_ / 4) + t;
    float4 acc = make_float4(0.f, 0.f, 0.f, 0.f);
#pragma unroll
    for (int r = 0; r < ROWS_PER_CHUNK; ++r) {
        float4 v = src[(size_t)r * (E_ / 4)];
        acc.x += v.x; acc.y += v.y; acc.z += v.z; acc.w += v.w;
    }
    partial[(size_t)(b * SCHUNK + chunk) * (E_ / 4) + t] = acc;
}

// ------------------------------------------------------------------
// Kernel A2: reduce partials -> colsum[b*E + e].
// 4-way split-K per column + LDS combine.
// grid = B_*E_/64 = 32 blocks, 256 threads.
// Thread (q, cl): q = tid>>6 (K-quarter), cl = tid&63 (local column).
// Each sums SCHUNK/4 = 64 chunks; coalesced 256 B per wave-read.
// ------------------------------------------------------------------
__global__ void reduce_colsum_kernel(const float* __restrict__ partial,
                                     float* __restrict__ colsum) {
    const int cl = threadIdx.x & 63;
    const int q = threadIdx.x >> 6;
    const int col = blockIdx.x * 64 + cl;  // global column 0..B*E-1
    const int b = col >> 10;               // / E_
    const int e = col & (E_ - 1);

    float acc = 0.f;
#pragma unroll 8
    for (int cc = 0; cc < SCHUNK / 4; ++cc) {
        const int chunk = q * (SCHUNK / 4) + cc;
        acc += partial[(size_t)(b * SCHUNK + chunk) * E_ + e];
    }

    __shared__ float red[4][64];
    red[q][cl] = acc;
    __syncthreads();
    if (q == 0) {
        colsum[col] = red[0][cl] + red[1][cl] + red[2][cl] + red[3][cl];
    }
}

// ------------------------------------------------------------------
// Kernel B: r[b,j] = dot(colsum[b,:], Wv[j,:]) + S*bv[j]
// One wave per output j; 4 waves (4 outputs) per block; 512 blocks.
// ------------------------------------------------------------------
__global__ void gemv_r_kernel(const float* __restrict__ colsum,
                              const float* __restrict__ Wv,
                              const float* __restrict__ bv,
                              float* __restrict__ r) {
    const int wave = threadIdx.x >> 6;
    const int lane = threadIdx.x & 63;
    const int out_idx = blockIdx.x * 4 + wave;  // 0..B*E-1
    const int b = out_idx >> 10;                // / E_
    const int j = out_idx & (E_ - 1);

    const float4* wrow = (const float4*)(Wv + (size_t)j * E_);
    const float4* cs = (const float4*)(colsum + (size_t)b * E_);

    float acc = 0.f;
#pragma unroll
    for (int i = 0; i < 4; ++i) {
        float4 w = wrow[lane + 64 * i];
        float4 c = cs[lane + 64 * i];
        acc += w.x * c.x + w.y * c.y + w.z * c.z + w.w * c.w;
    }
    // wave-wide reduction (64 lanes)
#pragma unroll
    for (int off = 32; off > 0; off >>= 1) acc += __shfl_down(acc, off, 64);

    if (lane == 0) r[out_idx] = acc + (float)S_ * bv[j];
}

// ------------------------------------------------------------------
// Kernel C: broadcast r over the q axis.
// out[b,q,j] = r[b,j]; float4 granularity; wave stores 1 KB contiguous.
// grid = 4096 blocks, 256 threads, 1 float4 each.
// ------------------------------------------------------------------
__global__ void broadcast_out_kernel(const float4* __restrict__ r,
                                     float4* __restrict__ out) {
    const size_t idx = (size_t)blockIdx.x * 256 + threadIdx.x;  // float4 index
    const int j4 = (int)(idx & 255);         // E/4 = 256 float4 cols
    const int b = (int)(idx >> 19);          // / (S_ * 256)
    out[idx] = r[(b << 8) + j4];
}

// ------------------------------------------------------------------
// kernel_launch
// Inputs (setup_inputs order):
//   0: values [B,S,E] f32   (used)
//   1: keys                 (unused - einsum degeneracy: 'bhqk,bvhd->bqhd'
//   2: queries               sums attn over k (=1) and v independently)
//   3: Wq  4: bq  5: Wk  6: bk   (unused)
//   7: Wv [E,E] f32 (used)  8: bv [E] f32 (used)
// Output: [B,S,H,D] f32 = [2,2048,16,64] flat = [B,S,E].
// ------------------------------------------------------------------
extern "C" void kernel_launch(void* const* d_in, const int* in_sizes, int n_in,
                              void* d_out, int out_size, void* d_ws, size_t ws_size,
                              hipStream_t stream) {
    const float* values = (const float*)d_in[0];
    const float* Wv = (const float*)d_in[7];
    const float* bv = (const float*)d_in[8];
    float* out = (float*)d_out;

    // ws layout (floats): partial[B*SCHUNK*E], colsum[B*E], r[B*E]
    float* partial = (float*)d_ws;
    float* colsum = partial + (size_t)B_ * SCHUNK * E_;
    float* r = colsum + (size_t)B_ * E_;

    partial_colsum_kernel<<<B_ * SCHUNK, 256, 0, stream>>>((const float4*)values,
                                                           (float4*)partial);
    reduce_colsum_kernel<<<(B_ * E_) / 64, 256, 0, stream>>>(partial, colsum);
    gemv_r_kernel<<<(B_ * E_) / 4, 256, 0, stream>>>(colsum, Wv, bv, r);
    broadcast_out_kernel<<<(size_t)(B_ * S_ * E_) / 4 / 256, 256, 0, stream>>>(
        (const float4*)r, (float4*)out);
}